// Round 17
// baseline (438.933 us; speedup 1.0000x reference)
//
#include <hip/hip_runtime.h>
#include <stdint.h>

typedef __attribute__((ext_vector_type(8))) short bf16x8;
typedef __attribute__((ext_vector_type(4))) float f32x4;
typedef __attribute__((ext_vector_type(16))) float f32x16;
typedef unsigned short ushortT;

#define DEV static __device__ __forceinline__

DEV unsigned short f2bf(float x) {
  union { float f; unsigned u; } v; v.f = x;
  unsigned r = v.u + 0x7fffu + ((v.u >> 16) & 1u);
  return (unsigned short)(r >> 16);
}
DEV float bf2f(unsigned short b) {
  union { unsigned u; float f; } v; v.u = ((unsigned)b) << 16; return v.f;
}
DEV void gll16(const void* g, void* l) {
  __builtin_amdgcn_global_load_lds((const __attribute__((address_space(1))) void*)g,
                                   (__attribute__((address_space(3))) void*)l, 16, 0, 0);
}

#define VMW(n) asm volatile("s_waitcnt vmcnt(" #n ")" ::: "memory")
#define RAWBAR() __builtin_amdgcn_s_barrier()
#define SCHED0() __builtin_amdgcn_sched_barrier(0)

// ---------------- prep: W1t/W2t bf16 transposes + gate fold ----------------
__global__ void kPrep(const float* __restrict__ W1, const float* __restrict__ W2,
                      const float* __restrict__ Wg, const float* __restrict__ ln_g,
                      ushortT* __restrict__ W1t, ushortT* __restrict__ W2t,
                      float* __restrict__ gw, float* __restrict__ wgm) {
  const size_t t = (size_t)blockIdx.x * 256 + threadIdx.x;
  if (t < 524288) {            // W1 (512x1024) -> W1t[n][k] (1024x512)
    int n = (int)(t & 1023), k = (int)(t >> 10);
    W1t[(size_t)n * 512 + k] = f2bf(W1[(size_t)k * 1024 + n]);
  } else if (t < 1048576) {    // W2 (1024x512) -> W2t[n][k] (512x1024)
    size_t u = t - 524288;
    int n = (int)(u & 511), k = (int)(u >> 9);
    W2t[(size_t)n * 1024 + k] = f2bf(W2[(size_t)k * 512 + n]);
  } else if (t < 1048576 + 512) {
    int c = (int)(t - 1048576);
    float s = 0.f;
    for (int j = 0; j < 16; ++j) s += Wg[c * 16 + j];
    float m = s * (1.0f / 16.0f);
    wgm[c] = m;
    gw[c] = ln_g[c] * m;
  }
}

__global__ void kPrep2(const float* __restrict__ gw, const float* __restrict__ wgm,
                       const float* __restrict__ ln_b, const float* __restrict__ bg,
                       float* __restrict__ consts) {
  const int tid = threadIdx.x;  // 512
  float a = gw[tid];
  float c = ln_b[tid] * wgm[tid];
  #pragma unroll
  for (int s = 1; s < 64; s <<= 1) { a += __shfl_xor(a, s); c += __shfl_xor(c, s); }
  __shared__ float red[8][2];
  const int wv = tid >> 6, ln = tid & 63;
  if (ln == 0) { red[wv][0] = a; red[wv][1] = c; }
  __syncthreads();
  if (tid == 0) {
    float Cg = 0, Cb0 = 0;
    for (int k = 0; k < 8; ++k) { Cg += red[k][0]; Cb0 += red[k][1]; }
    float bgm = 0;
    for (int j = 0; j < 16; ++j) bgm += bg[j];
    bgm *= (1.0f / 16.0f);
    consts[0] = Cg; consts[1] = Cb0 + bgm; consts[2] = bgm;
  }
}

// ---------------- embed gather -> h bf16 ----------------
__global__ void kEmbed(const int* __restrict__ seq, const float* __restrict__ embed,
                       ushortT* __restrict__ h) {
  const size_t t = (size_t)blockIdx.x * 256 + threadIdx.x;  // 4,194,304
  const size_t row = t >> 6;
  const int seg = (int)(t & 63) * 8;
  const int tok = seq[row];
  const float4* src = (const float4*)(embed + (size_t)tok * 512 + seg);
  float4 x = src[0], y = src[1];
  uint4 u;
  u.x = (unsigned)f2bf(x.x) | ((unsigned)f2bf(x.y) << 16);
  u.y = (unsigned)f2bf(x.z) | ((unsigned)f2bf(x.w) << 16);
  u.z = (unsigned)f2bf(y.x) | ((unsigned)f2bf(y.y) << 16);
  u.w = (unsigned)f2bf(y.z) | ((unsigned)f2bf(y.w) << 16);
  *(uint4*)(h + row * 512 + seg) = u;
}

// ============ GEMM1: 256x128 block, BK=32, ring-3, 2-tile-deep prefetch ============
// 8 waves: wr=w>>1 (0..3) m, wc=w&1 (0..1) n; wave tile 64x64, acc[4][4].
// LDS (ushorts): A buf i at [i*8192 + c*512] c=0..15; B buf i at [24576 + i*4096 + c*512] c=0..7.
__global__ __launch_bounds__(512, 2) void kG1p(const ushortT* __restrict__ h,
                                               const ushortT* __restrict__ W1t,
                                               const float* __restrict__ b1,
                                               ushortT* __restrict__ Y) {
  __shared__ __align__(16) ushortT SH[36864];       // 72 KB (ring-3 A|B; bounce overlays)
  const int tid = threadIdx.x, w = tid >> 6, l = tid & 63;
  const int b = blockIdx.x, xcd = b & 7, loc = b >> 3;   // loc 0..127
  const int nt = loc & 7, mtl = loc >> 3;                // 8 nt x 16 mtl
  const size_t m0 = (size_t)(xcd * 16 + mtl) * 256;
  const int n0 = nt * 128;
  const int rl = l & 15, gq = l >> 4;
  f32x4 acc[4][4] = {};

  auto stage = [&](int buf, int k0) {                // 3 gll16/thread
    #pragma unroll
    for (int q = 0; q < 2; ++q) {
      const int c = w * 2 + q;                       // A rowblock 0..15
      gll16(h + (m0 + c * 16 + rl) * 512 + k0 + gq * 8, &SH[buf * 8192 + c * 512]);
    }
    gll16(W1t + (size_t)(n0 + w * 16 + rl) * 512 + k0 + gq * 8, &SH[24576 + buf * 4096 + w * 512]);
  };

  const int wr = w >> 1, wc = w & 1, l8 = l * 8;
  auto compute = [&](int buf) {
    bf16x8 a[4], bb[4];
    #pragma unroll
    for (int i = 0; i < 4; ++i)
      a[i] = *(const bf16x8*)&SH[buf * 8192 + (wr * 4 + i) * 512 + l8];
    #pragma unroll
    for (int j = 0; j < 4; ++j)
      bb[j] = *(const bf16x8*)&SH[24576 + buf * 4096 + (wc * 4 + j) * 512 + l8];
    #pragma unroll
    for (int i = 0; i < 4; ++i)
      #pragma unroll
      for (int j = 0; j < 4; ++j)
        acc[i][j] = __builtin_amdgcn_mfma_f32_16x16x32_bf16(a[i], bb[j], acc[i][j], 0, 0, 0);
  };

  stage(0, 0); stage(1, 32); stage(2, 64);
  for (int t = 0; t < 16; ++t) {
    if (t <= 13) { VMW(6); } else if (t == 14) { VMW(3); } else { VMW(0); }
    RAWBAR(); SCHED0();
    compute(t % 3);
    SCHED0(); RAWBAR();
    if (t <= 12) stage(t % 3, (t + 3) * 32);
  }

  float bv[4];
  #pragma unroll
  for (int j = 0; j < 4; ++j) bv[j] = b1[n0 + wc * 64 + j * 16 + rl];

  // LDS-bounce epilogue: 4 passes of 64 rows x 128 cols, row stride 136 ushorts
  #pragma unroll
  for (int P = 0; P < 4; ++P) {
    __syncthreads();
    if (wr == P) {
      #pragma unroll
      for (int i = 0; i < 4; ++i) {
        #pragma unroll
        for (int j = 0; j < 4; ++j) {
          const int cl = wc * 64 + j * 16 + rl;
          #pragma unroll
          for (int r = 0; r < 4; ++r) {
            const int lr = i * 16 + gq * 4 + r;
            float v = acc[i][j][r] + bv[j];
            v = v > 0.0f ? v : 0.0f;
            SH[lr * 136 + cl] = f2bf(v);
          }
        }
      }
    }
    __syncthreads();
    #pragma unroll
    for (int it = 0; it < 2; ++it) {
      const int row = it * 32 + (tid >> 4);
      const int c8 = (tid & 15) * 8;
      uint4 v = *(const uint4*)&SH[row * 136 + c8];
      *(uint4*)&Y[(m0 + P * 64 + row) * 1024 + n0 + c8] = v;
    }
  }
}

// ============ GEMM2: 256x128 block, BK=32, ring-3, 2-tile-deep prefetch; K=1024 ============
__global__ __launch_bounds__(512, 2) void kG2p(const ushortT* __restrict__ Yb,
                                               const ushortT* __restrict__ W2t,
                                               const ushortT* __restrict__ h,
                                               const float* __restrict__ b2,
                                               const float* __restrict__ gw,
                                               float* __restrict__ partS, int R0) {
  __shared__ __align__(16) ushortT SH[36864];       // 72 KB
  __shared__ float part[256][2][3];
  const int tid = threadIdx.x, w = tid >> 6, l = tid & 63;
  const int b = blockIdx.x, xcd = b & 7, loc = b >> 3;   // loc 0..63
  const int nt = loc & 3, mtl = loc >> 2;                // 4 nt x 16 mtl
  const size_t m0 = (size_t)(xcd * 16 + mtl) * 256;
  const int n0 = nt * 128;
  const int rl = l & 15, gq = l >> 4;
  f32x4 acc[4][4] = {};

  auto stage = [&](int buf, int k0) {                // 3 gll16/thread
    #pragma unroll
    for (int q = 0; q < 2; ++q) {
      const int c = w * 2 + q;
      gll16(Yb + (m0 + c * 16 + rl) * 1024 + k0 + gq * 8, &SH[buf * 8192 + c * 512]);
    }
    gll16(W2t + (size_t)(n0 + w * 16 + rl) * 1024 + k0 + gq * 8, &SH[24576 + buf * 4096 + w * 512]);
  };

  const int wr = w >> 1, wc = w & 1, l8 = l * 8;
  auto compute = [&](int buf) {
    bf16x8 a[4], bb[4];
    #pragma unroll
    for (int i = 0; i < 4; ++i)
      a[i] = *(const bf16x8*)&SH[buf * 8192 + (wr * 4 + i) * 512 + l8];
    #pragma unroll
    for (int j = 0; j < 4; ++j)
      bb[j] = *(const bf16x8*)&SH[24576 + buf * 4096 + (wc * 4 + j) * 512 + l8];
    #pragma unroll
    for (int i = 0; i < 4; ++i)
      #pragma unroll
      for (int j = 0; j < 4; ++j)
        acc[i][j] = __builtin_amdgcn_mfma_f32_16x16x32_bf16(a[i], bb[j], acc[i][j], 0, 0, 0);
  };

  stage(0, 0); stage(1, 32); stage(2, 64);
  for (int t = 0; t < 32; ++t) {
    if (t <= 29) { VMW(6); } else if (t == 30) { VMW(3); } else { VMW(0); }
    RAWBAR(); SCHED0();
    compute(t % 3);
    SCHED0(); RAWBAR();
    if (t <= 28) stage(t % 3, (t + 3) * 32);
  }

  // epilogue: exact partial stats over this block's 128 cols
  #pragma unroll
  for (int i = 0; i < 4; ++i) {
    #pragma unroll
    for (int r = 0; r < 4; ++r) {
      const int rowl = wr * 64 + i * 16 + gq * 4 + r;
      const size_t grow = (size_t)R0 + m0 + rowl;
      float s1 = 0, s2 = 0, s3 = 0;
      #pragma unroll
      for (int j = 0; j < 4; ++j) {
        const int col = n0 + wc * 64 + j * 16 + rl;
        const float z = acc[i][j][r] + b2[col] + bf2f(h[grow * 512 + col]);
        s1 += z; s2 += z * z; s3 += z * gw[col];
      }
      #pragma unroll
      for (int s = 1; s < 16; s <<= 1) {
        s1 += __shfl_xor(s1, s);
        s2 += __shfl_xor(s2, s);
        s3 += __shfl_xor(s3, s);
      }
      if (rl == 0) { part[rowl][wc][0] = s1; part[rowl][wc][1] = s2; part[rowl][wc][2] = s3; }
    }
  }
  __syncthreads();
  if (tid < 256) {
    const size_t grow = (size_t)R0 + m0 + tid;
    const float S1 = part[tid][0][0] + part[tid][1][0];
    const float S2 = part[tid][0][1] + part[tid][1][1];
    const float S3 = part[tid][0][2] + part[tid][1][2];
    float* p = partS + grow * 16 + nt * 4;
    p[0] = S1; p[1] = S2; p[2] = S3;
  }
}

// ---------------- fold partials -> score; approx top-4 + margin candidates ----------------
__global__ void kTop(const float* __restrict__ partS, const float* __restrict__ consts,
                     float* __restrict__ scores, int* __restrict__ cidx,
                     int* __restrict__ ccnt) {
  const int b = blockIdx.x, tid = threadIdx.x;
  const float Cg = consts[0], Cb = consts[1];
  float v0 = -1e30f, v1 = -1e30f, v2 = -1e30f, v3 = -1e30f;
  for (int i = tid; i < 2047; i += 256) {
    const size_t row = (size_t)b * 2048 + i;
    const float* p = partS + row * 16;
    const float S1 = p[0] + p[4] + p[8] + p[12];
    const float S2 = p[1] + p[5] + p[9] + p[13];
    const float S3 = p[2] + p[6] + p[10] + p[14];
    const float mu = S1 * (1.0f / 512.0f);
    const float var = S2 * (1.0f / 512.0f) - mu * mu;
    const float x = rsqrtf(var + 1e-5f) * (S3 - mu * Cg) + Cb;
    scores[row] = x;
    if (x > v3) {
      if (x > v0)      { v3 = v2; v2 = v1; v1 = v0; v0 = x; }
      else if (x > v1) { v3 = v2; v2 = v1; v1 = x; }
      else if (x > v2) { v3 = v2; v2 = x; }
      else             { v3 = x; }
    }
  }
  __shared__ float lv[256][4];
  lv[tid][0] = v0; lv[tid][1] = v1; lv[tid][2] = v2; lv[tid][3] = v3;
  __syncthreads();
  for (int s = 128; s > 0; s >>= 1) {
    if (tid < s) {
      float m[8] = { lv[tid][0], lv[tid][1], lv[tid][2], lv[tid][3],
                     lv[tid + s][0], lv[tid + s][1], lv[tid + s][2], lv[tid + s][3] };
      #pragma unroll
      for (int k = 0; k < 4; ++k) {
        int mx = k;
        #pragma unroll
        for (int j2 = k + 1; j2 < 8; ++j2) if (m[j2] > m[mx]) mx = j2;
        const float tv = m[k]; m[k] = m[mx]; m[mx] = tv;
        lv[tid][k] = m[k];
      }
    }
    __syncthreads();
  }
  __shared__ int cnt;
  __shared__ float thr;
  if (tid == 0) { thr = lv[0][3] - 0.03f; cnt = 0; }
  __syncthreads();
  const float th = thr;
  const float* sc = scores + (size_t)b * 2048;
  for (int i = tid; i < 2047; i += 256) {
    if (sc[i] >= th) {
      const int p = atomicAdd(&cnt, 1);
      if (p < 24) cidx[b * 24 + p] = i;
    }
  }
  __syncthreads();
  if (tid == 0) ccnt[b] = cnt < 24 ? cnt : 24;
}

__global__ void kCompact(const int* __restrict__ ccnt, const int* __restrict__ cidx,
                         int* __restrict__ offs, int* __restrict__ rowsb,
                         int* __restrict__ rowsl, int* __restrict__ plast,
                         int* __restrict__ nrp) {
  const int tid = threadIdx.x;
  if (tid >= 32) return;
  int off = 0, nc = 0;
  for (int k = 0; k < 32; ++k) { const int c = ccnt[k]; if (k < tid) off += c; nc += c; }
  offs[tid] = off;
  const int cnt = ccnt[tid];
  for (int j = 0; j < cnt; ++j) { rowsb[off + j] = tid; rowsl[off + j] = cidx[tid * 24 + j]; }
  rowsb[nc + tid] = tid; rowsl[nc + tid] = 2047; plast[tid] = nc + tid;
  if (tid == 0) { offs[32] = nc; nrp[0] = nc + 32; }
}

// ---------------- exact f32 rescue path ----------------
__global__ void kGather(const int* __restrict__ nrp, const int* __restrict__ rowsb,
                        const int* __restrict__ rowsl, const int* __restrict__ seq,
                        const float* __restrict__ embed, float* __restrict__ H2) {
  const int p = blockIdx.x;
  if (p >= nrp[0]) return;
  const int b = rowsb[p], lr = rowsl[p];
  const size_t gr = (size_t)b * 2048 + lr;
  const int tok = seq[gr];
  const float* src = embed + (size_t)tok * 512;
  float* dst = H2 + (size_t)p * 512;
  for (int c = threadIdx.x; c < 512; c += 128) dst[c] = src[c];
}

__global__ __launch_bounds__(256) void kR1(const int* __restrict__ nrp,
                                           const float* __restrict__ H2,
                                           const float* __restrict__ W1,
                                           const float* __restrict__ b1,
                                           float* __restrict__ Y2) {
  const int p = blockIdx.y;
  if (p >= nrp[0]) return;
  const int col = blockIdx.x * 256 + threadIdx.x;
  __shared__ float hrow[512];
  for (int c = threadIdx.x; c < 512; c += 256) hrow[c] = H2[(size_t)p * 512 + c];
  __syncthreads();
  float a0 = 0, a1 = 0, a2 = 0, a3 = 0;
  #pragma unroll 4
  for (int k = 0; k < 512; k += 4) {
    a0 = fmaf(hrow[k + 0], W1[(size_t)(k + 0) * 1024 + col], a0);
    a1 = fmaf(hrow[k + 1], W1[(size_t)(k + 1) * 1024 + col], a1);
    a2 = fmaf(hrow[k + 2], W1[(size_t)(k + 2) * 1024 + col], a2);
    a3 = fmaf(hrow[k + 3], W1[(size_t)(k + 3) * 1024 + col], a3);
  }
  const float v = a0 + a1 + a2 + a3 + b1[col];
  Y2[(size_t)p * 1024 + col] = v > 0.0f ? v : 0.0f;
}

__global__ __launch_bounds__(256) void kR2(const int* __restrict__ nrp,
                                           const float* __restrict__ Y2,
                                           const float* __restrict__ W2,
                                           const float* __restrict__ b2,
                                           float* __restrict__ F2) {
  const int p = blockIdx.y;
  if (p >= nrp[0]) return;
  const int col = blockIdx.x * 256 + threadIdx.x;
  __shared__ float yrow[1024];
  for (int c = threadIdx.x; c < 1024; c += 256) yrow[c] = Y2[(size_t)p * 1024 + c];
  __syncthreads();
  float a0 = 0, a1 = 0, a2 = 0, a3 = 0;
  #pragma unroll 4
  for (int k = 0; k < 1024; k += 4) {
    a0 = fmaf(yrow[k + 0], W2[(size_t)(k + 0) * 512 + col], a0);
    a1 = fmaf(yrow[k + 1], W2[(size_t)(k + 1) * 512 + col], a1);
    a2 = fmaf(yrow[k + 2], W2[(size_t)(k + 2) * 512 + col], a2);
    a3 = fmaf(yrow[k + 3], W2[(size_t)(k + 3) * 512 + col], a3);
  }
  F2[(size_t)p * 512 + col] = a0 + a1 + a2 + a3 + b2[col];
}

__global__ void kR3(const int* __restrict__ nrp, const float* __restrict__ H2,
                    const float* __restrict__ F2, const float* __restrict__ ln_g,
                    const float* __restrict__ ln_b, const float* __restrict__ wgm,
                    const float* __restrict__ consts, float* __restrict__ LNR,
                    float* __restrict__ cscore) {
  const int p = blockIdx.x;
  if (p >= nrp[0]) return;
  const int tid = threadIdx.x;  // 256
  const int c0 = tid, c1 = tid + 256;
  const float z0 = H2[(size_t)p * 512 + c0] + F2[(size_t)p * 512 + c0];
  const float z1 = H2[(size_t)p * 512 + c1] + F2[(size_t)p * 512 + c1];
  float s1 = z0 + z1, s2 = z0 * z0 + z1 * z1;
  #pragma unroll
  for (int s = 1; s < 64; s <<= 1) { s1 += __shfl_xor(s1, s); s2 += __shfl_xor(s2, s); }
  __shared__ float red[4][2];
  __shared__ float stats[2];
  const int wv = tid >> 6, ln = tid & 63;
  if (ln == 0) { red[wv][0] = s1; red[wv][1] = s2; }
  __syncthreads();
  if (tid == 0) {
    const float S1 = red[0][0] + red[1][0] + red[2][0] + red[3][0];
    const float S2 = red[0][1] + red[1][1] + red[2][1] + red[3][1];
    const float mu = S1 * (1.0f / 512.0f);
    const float var = S2 * (1.0f / 512.0f) - mu * mu;
    stats[0] = mu; stats[1] = rsqrtf(var + 1e-5f);
  }
  __syncthreads();
  const float mu = stats[0], rstd = stats[1];
  const float l0 = (z0 - mu) * rstd * ln_g[c0] + ln_b[c0];
  const float l1 = (z1 - mu) * rstd * ln_g[c1] + ln_b[c1];
  LNR[(size_t)p * 512 + c0] = l0;
  LNR[(size_t)p * 512 + c1] = l1;
  float sp = l0 * wgm[c0] + l1 * wgm[c1];
  #pragma unroll
  for (int s = 1; s < 64; s <<= 1) sp += __shfl_xor(sp, s);
  if (ln == 0) red[wv][0] = sp;
  __syncthreads();
  if (tid == 0) cscore[p] = red[0][0] + red[1][0] + red[2][0] + red[3][0] + consts[2];
}

// ---------------- exact select + attention -> ctx (+ bf16 copy) ----------------
__global__ void kSel(const int* __restrict__ ccnt, const int* __restrict__ offs,
                     const int* __restrict__ rowsl, const int* __restrict__ plast,
                     const float* __restrict__ cscore, const float* __restrict__ LNR,
                     const float* __restrict__ Wr, const float* __restrict__ br,
                     float* __restrict__ ctx, ushortT* __restrict__ ctxB) {
  const int b = blockIdx.x, tid = threadIdx.x;  // 256
  __shared__ int psel[4];
  __shared__ float lnl[512];
  __shared__ float qs[512];
  __shared__ float aw[4];
  __shared__ float red[4][4];
  if (tid == 0) {
    const int cnt = ccnt[b], off = offs[b];
    float scv[24]; int lr[24]; bool tk[24];
    for (int j = 0; j < cnt; ++j) { scv[j] = cscore[off + j]; lr[j] = rowsl[off + j]; tk[j] = false; }
    for (int k = 0; k < 4; ++k) {
      int best = -1;
      for (int j = 0; j < cnt; ++j) {
        if (tk[j]) continue;
        if (best < 0 || scv[j] > scv[best] || (scv[j] == scv[best] && lr[j] < lr[best])) best = j;
      }
      tk[best] = true;
      psel[k] = off + best;
    }
  }
  __syncthreads();
  const int pl = plast[b];
  for (int c = tid; c < 512; c += 256) lnl[c] = LNR[(size_t)pl * 512 + c];
  __syncthreads();
  #pragma unroll
  for (int cc = 0; cc < 2; ++cc) {
    const int col = tid + cc * 256;
    float s = br[col];
    for (int d = 0; d < 512; ++d) s = fmaf(lnl[d], Wr[(size_t)d * 512 + col], s);
    qs[col] = s;
  }
  __syncthreads();
  const int p0 = psel[0], p1 = psel[1], p2 = psel[2], p3 = psel[3];
  float ps[4] = {0, 0, 0, 0};
  for (int d = tid; d < 512; d += 256) {
    const float qv = qs[d];
    ps[0] = fmaf(qv, LNR[(size_t)p0 * 512 + d], ps[0]);
    ps[1] = fmaf(qv, LNR[(size_t)p1 * 512 + d], ps[1]);
    ps[2] = fmaf(qv, LNR[(size_t)p2 * 512 + d], ps[2]);
    ps[3] = fmaf(qv, LNR[(size_t)p3 * 512 + d], ps[3]);
  }
  #pragma unroll
  for (int s = 1; s < 64; s <<= 1) {
    ps[0] += __shfl_xor(ps[0], s); ps[1] += __shfl_xor(ps[1], s);
    ps[2] += __shfl_xor(ps[2], s); ps[3] += __shfl_xor(ps[3], s);
  }
  const int wv = tid >> 6, ln = tid & 63;
  if (ln == 0) { red[wv][0] = ps[0]; red[wv][1] = ps[1]; red[wv][2] = ps[2]; red[wv][3] = ps[3]; }
  __syncthreads();
  if (tid == 0) {
    const float s0 = red[0][0] + red[1][0] + red[2][0] + red[3][0];
    const float s1 = red[0][1] + red[1][1] + red[2][1] + red[3][1];
    const float s2 = red[0][2] + red[1][2] + red[2][2] + red[3][2];
    const float s3 = red[0][3] + red[1][3] + red[2][3] + red[3][3];
    const float m = fmaxf(fmaxf(fmaxf(s0, s1), fmaxf(s2, s3)), 0.0f);
    const float e0 = expf(s0 - m), e1 = expf(s1 - m), e2 = expf(s2 - m), e3 = expf(s3 - m);
    const float den = e0 + e1 + e2 + e3 + 12.0f * expf(-m);
    aw[0] = e0 / den; aw[1] = e1 / den; aw[2] = e2 / den; aw[3] = e3 / den;
  }
  __syncthreads();
  const float a0 = aw[0], a1 = aw[1], a2 = aw[2], a3 = aw[3];
  #pragma unroll
  for (int cc = 0; cc < 2; ++cc) {
    const int col = tid + cc * 256;
    const float v = a0 * LNR[(size_t)p0 * 512 + col] + a1 * LNR[(size_t)p1 * 512 + col]
                  + a2 * LNR[(size_t)p2 * 512 + col] + a3 * LNR[(size_t)p3 * 512 + col];
    ctx[(size_t)b * 512 + col] = v;
    ctxB[(size_t)b * 512 + col] = f2bf(v);
  }
}

// ---------------- out = ctx @ Wo + bo via MFMA 32x32x16, split-K=4 ----------------
__global__ __launch_bounds__(512) void kOutM(const ushortT* __restrict__ ctxB,
                                             const float* __restrict__ Wo,
                                             float* __restrict__ partial) {
  const int tid = threadIdx.x, w = tid >> 6, l = tid & 63;
  const int ky = blockIdx.y;                 // K-quarter
  int col = blockIdx.x * 256 + w * 32 + (l & 31);
  const bool cv = col < 50257;
  if (!cv) col = 50256;
  const int kg = (l >> 5) * 8;
  const int kb = ky * 128;
  bf16x8 afr[8];
  #pragma unroll
  for (int ks = 0; ks < 8; ++ks)
    afr[ks] = *(const bf16x8*)&ctxB[(size_t)(l & 31) * 512 + kb + ks * 16 + kg];
  f32x16 acc = {};
  #pragma unroll
  for (int ks = 0; ks < 8; ++ks) {
    const float* wp = Wo + (size_t)(kb + ks * 16 + kg) * 50257 + col;
    float wv[8];
    #pragma unroll
    for (int j = 0; j < 8; ++j) wv[j] = wp[(size_t)j * 50257];
    bf16x8 bfr;
    #pragma unroll
    for (int j = 0; j < 8; ++j) bfr[j] = (short)f2bf(wv[j]);
    acc = __builtin_amdgcn_mfma_f32_32x32x16_bf16(afr[ks], bfr, acc, 0, 0, 0);
  }
  if (cv) {
    #pragma unroll
    for (int r = 0; r < 16; ++r) {
      const int row = (r & 3) + 8 * (r >> 2) + 4 * (l >> 5);
      partial[((size_t)ky * 32 + row) * 50257 + col] = acc[r];
    }
  }
}

__global__ __launch_bounds__(256) void kOutRed(const float* __restrict__ partial,
                                               const float* __restrict__ bo,
                                               float* __restrict__ out) {
  const size_t i = (size_t)blockIdx.x * 256 + threadIdx.x;
  if (i >= (size_t)32 * 50257) return;
  const int col = (int)(i % 50257);
  float s = bo[col];
  #pragma unroll
  for (int q = 0; q < 4; ++q) s += partial[(size_t)q * 32 * 50257 + i];
  out[i] = s;
}

// ---------------- launch ----------------
extern "C" void kernel_launch(void* const* d_in, const int* in_sizes, int n_in,
                              void* d_out, int out_size, void* d_ws, size_t ws_size,
                              hipStream_t stream) {
  const int*   seq   = (const int*)  d_in[0];
  const float* embed = (const float*)d_in[1];
  const float* W1    = (const float*)d_in[2];
  const float* b1    = (const float*)d_in[3];
  const float* W2    = (const float*)d_in[4];
  const float* b2    = (const float*)d_in[5];
  const float* ln_g  = (const float*)d_in[6];
  const float* ln_b  = (const float*)d_in[7];
  const float* Wg    = (const float*)d_in[8];
  const float* bg    = (const float*)d_in[9];
  const float* Wr    = (const float*)d_in[10];
  const float* br    = (const float*)d_in[11];
  const float* Wo    = (const float*)d_in[12];
  const float* bo    = (const float*)d_in[13];
  float* out = (float*)d_out;
  char* ws = (char*)d_ws;

  ushortT* W1t   = (ushortT*)(ws + 0);
  ushortT* W2t   = (ushortT*)(ws + 1048576);
  float* gw      = (float*)(ws + 2097152);
  float* wgm     = (float*)(ws + 2099200);
  float* consts  = (float*)(ws + 2101248);
  ushortT* h     = (ushortT*)(ws + 2101504);     // 65536 x 512 bf16
  ushortT* Ybuf  = (ushortT*)(ws + 69210368);    // 32768 x 1024 bf16 (per chunk); dead after kG2p
  float* partial = (float*)(ws + 69210368);      // 4 x 32 x 50257 f32 (reuses Ybuf region, post-GEMM)
  float* scores  = (float*)(ws + 136319232);     // 65536 f32
  int* cidx      = (int*)(ws + 136581376);       // 32 x 24
  int* ccnt      = (int*)(ws + 136584448);
  int* offs      = (int*)(ws + 136584576);
  int* nrp       = (int*)(ws + 136584832);
  int* plast     = (int*)(ws + 136585088);
  int* rowsb     = (int*)(ws + 136585344);       // 832
  int* rowsl     = (int*)(ws + 136588672);       // 832
  float* partS   = (float*)(ws + 136592000);     // 65536 x 16 f32 (4MB); dead after kTop,
  float* H2      = (float*)(ws + 136592000);     //   then rescue buffers reuse the region
  float* Y2      = (float*)(ws + 138295936);     // 832 x 1024
  float* F2      = (float*)(ws + 141703808);     // 832 x 512
  float* LNR     = (float*)(ws + 143407744);     // 832 x 512
  float* csc     = (float*)(ws + 145111680);     // 832
  float* ctxb    = (float*)(ws + 145115008);     // 32 x 512 f32
  ushortT* ctxB  = (ushortT*)(ws + 145180544);   // 32 x 512 bf16

  kPrep <<<4098, 256, 0, stream>>>(W1, W2, Wg, ln_g, W1t, W2t, gw, wgm);
  kPrep2<<<1, 512, 0, stream>>>(gw, wgm, ln_b, bg, consts);
  kEmbed<<<16384, 256, 0, stream>>>(seq, embed, h);
  for (int c = 0; c < 2; ++c) {
    kG1p<<<1024, 512, 0, stream>>>(h + (size_t)c * 32768 * 512, W1t, b1, Ybuf);
    kG2p<<<512, 512, 0, stream>>>(Ybuf, W2t, h, b2, gw, partS, c * 32768);
  }
  kTop    <<<32, 256, 0, stream>>>(partS, consts, scores, cidx, ccnt);
  kCompact<<<1, 64, 0, stream>>>(ccnt, cidx, offs, rowsb, rowsl, plast, nrp);
  kGather <<<800, 128, 0, stream>>>(nrp, rowsb, rowsl, seq, embed, H2);
  kR1<<<dim3(4, 800), 256, 0, stream>>>(nrp, H2, W1, b1, Y2);
  kR2<<<dim3(2, 800), 256, 0, stream>>>(nrp, Y2, W2, b2, F2);
  kR3<<<800, 256, 0, stream>>>(nrp, H2, F2, ln_g, ln_b, wgm, consts, LNR, csc);
  kSel<<<32, 256, 0, stream>>>(ccnt, offs, rowsl, plast, csc, LNR, Wr, br, ctxb, ctxB);
  kOutM<<<dim3(197, 4), 512, 0, stream>>>(ctxB, Wo, partial);
  kOutRed<<<(32 * 50257 + 255) / 256, 256, 0, stream>>>(partial, bo, out);
}

// Round 18
// 434.180 us; speedup vs baseline: 1.0109x; 1.0109x over previous
//
#include <hip/hip_runtime.h>
#include <stdint.h>

typedef __attribute__((ext_vector_type(8))) short bf16x8;
typedef __attribute__((ext_vector_type(4))) float f32x4;
typedef __attribute__((ext_vector_type(16))) float f32x16;
typedef unsigned short ushortT;

#define DEV static __device__ __forceinline__

DEV unsigned short f2bf(float x) {
  union { float f; unsigned u; } v; v.f = x;
  unsigned r = v.u + 0x7fffu + ((v.u >> 16) & 1u);
  return (unsigned short)(r >> 16);
}
DEV float bf2f(unsigned short b) {
  union { unsigned u; float f; } v; v.u = ((unsigned)b) << 16; return v.f;
}
DEV void gll16(const void* g, void* l) {
  __builtin_amdgcn_global_load_lds((const __attribute__((address_space(1))) void*)g,
                                   (__attribute__((address_space(3))) void*)l, 16, 0, 0);
}

#define VMW(n) asm volatile("s_waitcnt vmcnt(" #n ")" ::: "memory")
#define RAWBAR() __builtin_amdgcn_s_barrier()
#define SCHED0() __builtin_amdgcn_sched_barrier(0)

// ---------------- prep: coalesced LDS-tile transposes + gate fold ----------------
__global__ __launch_bounds__(256) void kPrep(const float* __restrict__ W1,
                                             const float* __restrict__ W2,
                                             const float* __restrict__ Wg,
                                             const float* __restrict__ ln_g,
                                             ushortT* __restrict__ W1t,
                                             ushortT* __restrict__ W2t,
                                             float* __restrict__ gw,
                                             float* __restrict__ wgm) {
  __shared__ ushortT T[64][65];
  const int tid = threadIdx.x, bb = blockIdx.x;
  if (bb < 128) {              // W1 [512 k][1024 n] -> W1t [1024 n][512 k]
    const int nt = bb & 15, kt = bb >> 4;      // 16 n-tiles x 8 k-tiles
    const int k0 = kt * 64, n0 = nt * 64;
    #pragma unroll
    for (int it = 0; it < 16; ++it) {
      const int r = it * 4 + (tid >> 6);
      const int c = tid & 63;
      T[c][r] = f2bf(W1[(size_t)(k0 + r) * 1024 + n0 + c]);
    }
    __syncthreads();
    #pragma unroll
    for (int it = 0; it < 16; ++it) {
      const int r = it * 4 + (tid >> 6);
      const int c = tid & 63;
      W1t[(size_t)(n0 + r) * 512 + k0 + c] = T[r][c];
    }
  } else if (bb < 256) {       // W2 [1024 k][512 n] -> W2t [512 n][1024 k]
    const int u = bb - 128;
    const int nt = u & 7, kt = u >> 3;         // 8 n-tiles x 16 k-tiles
    const int k0 = kt * 64, n0 = nt * 64;
    #pragma unroll
    for (int it = 0; it < 16; ++it) {
      const int r = it * 4 + (tid >> 6);
      const int c = tid & 63;
      T[c][r] = f2bf(W2[(size_t)(k0 + r) * 512 + n0 + c]);
    }
    __syncthreads();
    #pragma unroll
    for (int it = 0; it < 16; ++it) {
      const int r = it * 4 + (tid >> 6);
      const int c = tid & 63;
      W2t[(size_t)(n0 + r) * 1024 + k0 + c] = T[r][c];
    }
  } else {                     // gate fold
    for (int c = tid; c < 512; c += 256) {
      float s = 0.f;
      for (int j = 0; j < 16; ++j) s += Wg[c * 16 + j];
      const float m = s * (1.0f / 16.0f);
      wgm[c] = m;
      gw[c] = ln_g[c] * m;
    }
  }
}

__global__ void kPrep2(const float* __restrict__ gw, const float* __restrict__ wgm,
                       const float* __restrict__ ln_b, const float* __restrict__ bg,
                       float* __restrict__ consts) {
  const int tid = threadIdx.x;  // 512
  float a = gw[tid];
  float c = ln_b[tid] * wgm[tid];
  #pragma unroll
  for (int s = 1; s < 64; s <<= 1) { a += __shfl_xor(a, s); c += __shfl_xor(c, s); }
  __shared__ float red[8][2];
  const int wv = tid >> 6, ln = tid & 63;
  if (ln == 0) { red[wv][0] = a; red[wv][1] = c; }
  __syncthreads();
  if (tid == 0) {
    float Cg = 0, Cb0 = 0;
    for (int k = 0; k < 8; ++k) { Cg += red[k][0]; Cb0 += red[k][1]; }
    float bgm = 0;
    for (int j = 0; j < 16; ++j) bgm += bg[j];
    bgm *= (1.0f / 16.0f);
    consts[0] = Cg; consts[1] = Cb0 + bgm; consts[2] = bgm;
  }
}

// ---------------- embed gather -> h bf16 ----------------
__global__ void kEmbed(const int* __restrict__ seq, const float* __restrict__ embed,
                       ushortT* __restrict__ h) {
  const size_t t = (size_t)blockIdx.x * 256 + threadIdx.x;  // 4,194,304
  const size_t row = t >> 6;
  const int seg = (int)(t & 63) * 8;
  const int tok = seq[row];
  const float4* src = (const float4*)(embed + (size_t)tok * 512 + seg);
  float4 x = src[0], y = src[1];
  uint4 u;
  u.x = (unsigned)f2bf(x.x) | ((unsigned)f2bf(x.y) << 16);
  u.y = (unsigned)f2bf(x.z) | ((unsigned)f2bf(x.w) << 16);
  u.z = (unsigned)f2bf(y.x) | ((unsigned)f2bf(y.y) << 16);
  u.w = (unsigned)f2bf(y.z) | ((unsigned)f2bf(y.w) << 16);
  *(uint4*)(h + row * 512 + seg) = u;
}

// ============ GEMM1: 256x256 block, BK=32, 8 waves (64x128 wave tile), ring-2 (R12-best) ============
__global__ __launch_bounds__(512, 2) void kG1p(const ushortT* __restrict__ h,
                                               const ushortT* __restrict__ W1t,
                                               const float* __restrict__ b1,
                                               ushortT* __restrict__ Y) {
  __shared__ __align__(16) ushortT SH[32768];       // 64 KB: ring-2 A|B, then C-bounce
  const int tid = threadIdx.x, w = tid >> 6, l = tid & 63;
  const int b = blockIdx.x, xcd = b & 7, loc = b >> 3;   // loc 0..63
  const int nt = loc & 3, mtl = loc >> 2;
  const size_t m0 = (size_t)(xcd * 16 + mtl) * 256;
  const int n0 = nt * 256;
  const int rl = l & 15, gq = l >> 4;
  f32x4 acc[4][8] = {};

  auto stage = [&](int buf, int k0) {
    #pragma unroll
    for (int q = 0; q < 2; ++q) {
      const int c = w * 2 + q;                       // rowblock 0..15
      gll16(h + (m0 + c * 16 + rl) * 512 + k0 + gq * 8, &SH[buf * 8192 + c * 512]);
      gll16(W1t + (size_t)(n0 + c * 16 + rl) * 512 + k0 + gq * 8, &SH[16384 + buf * 8192 + c * 512]);
    }
  };

  const int wr = w >> 1, wc = w & 1, l8 = l * 8;
  auto compute = [&](int buf) {
    bf16x8 a[4], bb[8];
    #pragma unroll
    for (int i = 0; i < 4; ++i)
      a[i] = *(const bf16x8*)&SH[buf * 8192 + (wr * 4 + i) * 512 + l8];
    #pragma unroll
    for (int j = 0; j < 8; ++j)
      bb[j] = *(const bf16x8*)&SH[16384 + buf * 8192 + (wc * 8 + j) * 512 + l8];
    #pragma unroll
    for (int i = 0; i < 4; ++i)
      #pragma unroll
      for (int j = 0; j < 8; ++j)
        acc[i][j] = __builtin_amdgcn_mfma_f32_16x16x32_bf16(a[i], bb[j], acc[i][j], 0, 0, 0);
  };

  stage(0, 0); stage(1, 32);
  for (int t = 0; t < 14; ++t) {
    VMW(4); RAWBAR(); SCHED0();
    compute(t & 1);
    SCHED0(); RAWBAR();
    stage(t & 1, (t + 2) * 32);
  }
  VMW(4); RAWBAR(); SCHED0(); compute(0); SCHED0(); RAWBAR();   // t=14
  VMW(0); RAWBAR(); SCHED0(); compute(1);                       // t=15

  float bv[8];
  #pragma unroll
  for (int j = 0; j < 8; ++j) bv[j] = b1[n0 + wc * 128 + j * 16 + rl];

  // LDS-bounce epilogue: 4 passes of 64 rows, row stride 266 ushorts
  #pragma unroll
  for (int P = 0; P < 4; ++P) {
    __syncthreads();
    if (wr == P) {
      #pragma unroll
      for (int i = 0; i < 4; ++i) {
        #pragma unroll
        for (int j = 0; j < 8; ++j) {
          const int cl = wc * 128 + j * 16 + rl;
          #pragma unroll
          for (int r = 0; r < 4; ++r) {
            const int lr = i * 16 + gq * 4 + r;
            float v = acc[i][j][r] + bv[j];
            v = v > 0.0f ? v : 0.0f;
            SH[lr * 266 + cl] = f2bf(v);
          }
        }
      }
    }
    __syncthreads();
    #pragma unroll
    for (int it = 0; it < 4; ++it) {
      const int row = it * 16 + (tid >> 5);
      const int c8 = (tid & 31) * 8;
      uint4 v = *(const uint4*)&SH[row * 266 + c8];
      *(uint4*)&Y[(m0 + P * 64 + row) * 1024 + n0 + c8] = v;
    }
  }
}

// ---------------- GEMM2: z = Y@W2+b2+h -> partial LN stats; ring-2 (R12-best) ----------------
__global__ __launch_bounds__(512, 2) void kG2p(const ushortT* __restrict__ Yb,
                                               const ushortT* __restrict__ W2t,
                                               const ushortT* __restrict__ h,
                                               const float* __restrict__ b2,
                                               const float* __restrict__ gw,
                                               float* __restrict__ partS, int R0) {
  __shared__ __align__(16) ushortT As[2][256 * 32];
  __shared__ __align__(16) ushortT Bs[2][256 * 32];
  __shared__ float part[256][2][3];
  const int tid = threadIdx.x, w = tid >> 6, l = tid & 63;
  const int b = blockIdx.x, xcd = b & 7, loc = b >> 3;   // loc 0..31
  const int nt = loc & 1, mtl = loc >> 1;
  const size_t m0 = (size_t)(xcd * 16 + mtl) * 256;
  const int n0 = nt * 256;
  const int rl = l & 15, gq = l >> 4;
  f32x4 acc[4][8] = {};

  auto stage = [&](int buf, int k0) {
    #pragma unroll
    for (int q = 0; q < 2; ++q) {
      const int c = w * 2 + q;
      gll16(Yb + (m0 + c * 16 + rl) * 1024 + k0 + gq * 8, &As[buf][c * 512]);
      gll16(W2t + (size_t)(n0 + c * 16 + rl) * 1024 + k0 + gq * 8, &Bs[buf][c * 512]);
    }
  };

  const int wr = w >> 1, wc = w & 1, l8 = l * 8;
  auto compute = [&](int buf) {
    bf16x8 a[4], bb[8];
    #pragma unroll
    for (int i = 0; i < 4; ++i)
      a[i] = *(const bf16x8*)&As[buf][(wr * 4 + i) * 512 + l8];
    #pragma unroll
    for (int j = 0; j < 8; ++j)
      bb[j] = *(const bf16x8*)&Bs[buf][(wc * 8 + j) * 512 + l8];
    #pragma unroll
    for (int i = 0; i < 4; ++i)
      #pragma unroll
      for (int j = 0; j < 8; ++j)
        acc[i][j] = __builtin_amdgcn_mfma_f32_16x16x32_bf16(a[i], bb[j], acc[i][j], 0, 0, 0);
  };

  stage(0, 0); stage(1, 32);
  for (int t = 0; t < 30; ++t) {
    VMW(4); RAWBAR(); SCHED0();
    compute(t & 1);
    SCHED0(); RAWBAR();
    stage(t & 1, (t + 2) * 32);
  }
  VMW(4); RAWBAR(); SCHED0(); compute(0); SCHED0(); RAWBAR();   // t=30
  VMW(0); RAWBAR(); SCHED0(); compute(1);                       // t=31

  // epilogue: exact partial stats over this block's 256 cols
  #pragma unroll
  for (int i = 0; i < 4; ++i) {
    #pragma unroll
    for (int r = 0; r < 4; ++r) {
      const int rowl = wr * 64 + i * 16 + gq * 4 + r;
      const size_t grow = (size_t)R0 + m0 + rowl;
      float s1 = 0, s2 = 0, s3 = 0;
      #pragma unroll
      for (int j = 0; j < 8; ++j) {
        const int col = n0 + wc * 128 + j * 16 + rl;
        const float z = acc[i][j][r] + b2[col] + bf2f(h[grow * 512 + col]);
        s1 += z; s2 += z * z; s3 += z * gw[col];
      }
      #pragma unroll
      for (int s = 1; s < 16; s <<= 1) {
        s1 += __shfl_xor(s1, s);
        s2 += __shfl_xor(s2, s);
        s3 += __shfl_xor(s3, s);
      }
      if (rl == 0) { part[rowl][wc][0] = s1; part[rowl][wc][1] = s2; part[rowl][wc][2] = s3; }
    }
  }
  __syncthreads();
  if (tid < 256) {
    const size_t grow = (size_t)R0 + m0 + tid;
    const float S1 = part[tid][0][0] + part[tid][1][0];
    const float S2 = part[tid][0][1] + part[tid][1][1];
    const float S3 = part[tid][0][2] + part[tid][1][2];
    float* p = partS + grow * 8 + nt * 4;
    p[0] = S1; p[1] = S2; p[2] = S3;
  }
}

// ---------------- fold partials -> score; approx top-4 + margin candidates ----------------
__global__ void kTop(const float* __restrict__ partS, const float* __restrict__ consts,
                     float* __restrict__ scores, int* __restrict__ cidx,
                     int* __restrict__ ccnt) {
  const int b = blockIdx.x, tid = threadIdx.x;
  const float Cg = consts[0], Cb = consts[1];
  float v0 = -1e30f, v1 = -1e30f, v2 = -1e30f, v3 = -1e30f;
  for (int i = tid; i < 2047; i += 256) {
    const size_t row = (size_t)b * 2048 + i;
    const float* p = partS + row * 8;
    const float S1 = p[0] + p[4];
    const float S2 = p[1] + p[5];
    const float S3 = p[2] + p[6];
    const float mu = S1 * (1.0f / 512.0f);
    const float var = S2 * (1.0f / 512.0f) - mu * mu;
    const float x = rsqrtf(var + 1e-5f) * (S3 - mu * Cg) + Cb;
    scores[row] = x;
    if (x > v3) {
      if (x > v0)      { v3 = v2; v2 = v1; v1 = v0; v0 = x; }
      else if (x > v1) { v3 = v2; v2 = v1; v1 = x; }
      else if (x > v2) { v3 = v2; v2 = x; }
      else             { v3 = x; }
    }
  }
  __shared__ float lv[256][4];
  lv[tid][0] = v0; lv[tid][1] = v1; lv[tid][2] = v2; lv[tid][3] = v3;
  __syncthreads();
  for (int s = 128; s > 0; s >>= 1) {
    if (tid < s) {
      float m[8] = { lv[tid][0], lv[tid][1], lv[tid][2], lv[tid][3],
                     lv[tid + s][0], lv[tid + s][1], lv[tid + s][2], lv[tid + s][3] };
      #pragma unroll
      for (int k = 0; k < 4; ++k) {
        int mx = k;
        #pragma unroll
        for (int j2 = k + 1; j2 < 8; ++j2) if (m[j2] > m[mx]) mx = j2;
        const float tv = m[k]; m[k] = m[mx]; m[mx] = tv;
        lv[tid][k] = m[k];
      }
    }
    __syncthreads();
  }
  __shared__ int cnt;
  __shared__ float thr;
  if (tid == 0) { thr = lv[0][3] - 0.03f; cnt = 0; }
  __syncthreads();
  const float th = thr;
  const float* sc = scores + (size_t)b * 2048;
  for (int i = tid; i < 2047; i += 256) {
    if (sc[i] >= th) {
      const int p = atomicAdd(&cnt, 1);
      if (p < 24) cidx[b * 24 + p] = i;
    }
  }
  __syncthreads();
  if (tid == 0) ccnt[b] = cnt < 24 ? cnt : 24;
}

__global__ void kCompact(const int* __restrict__ ccnt, const int* __restrict__ cidx,
                         int* __restrict__ offs, int* __restrict__ rowsb,
                         int* __restrict__ rowsl, int* __restrict__ plast,
                         int* __restrict__ nrp) {
  const int tid = threadIdx.x;
  if (tid >= 32) return;
  int off = 0, nc = 0;
  for (int k = 0; k < 32; ++k) { const int c = ccnt[k]; if (k < tid) off += c; nc += c; }
  offs[tid] = off;
  const int cnt = ccnt[tid];
  for (int j = 0; j < cnt; ++j) { rowsb[off + j] = tid; rowsl[off + j] = cidx[tid * 24 + j]; }
  rowsb[nc + tid] = tid; rowsl[nc + tid] = 2047; plast[tid] = nc + tid;
  if (tid == 0) { offs[32] = nc; nrp[0] = nc + 32; }
}

// ---------------- exact f32 rescue path (gather fused into kR1) ----------------
__global__ __launch_bounds__(256) void kR1(const int* __restrict__ nrp,
                                           const int* __restrict__ rowsb,
                                           const int* __restrict__ rowsl,
                                           const int* __restrict__ seq,
                                           const float* __restrict__ embed,
                                           float* __restrict__ H2,
                                           const float* __restrict__ W1,
                                           const float* __restrict__ b1,
                                           float* __restrict__ Y2) {
  const int p = blockIdx.y;
  if (p >= nrp[0]) return;
  const int b = rowsb[p], lr = rowsl[p];
  const int tok = seq[(size_t)b * 2048 + lr];
  const float* src = embed + (size_t)tok * 512;
  const int col = blockIdx.x * 256 + threadIdx.x;
  __shared__ float hrow[512];
  for (int c = threadIdx.x; c < 512; c += 256) {
    const float v = src[c];
    hrow[c] = v;
    if (blockIdx.x == 0) H2[(size_t)p * 512 + c] = v;
  }
  __syncthreads();
  float a0 = 0, a1 = 0, a2 = 0, a3 = 0;
  #pragma unroll 4
  for (int k = 0; k < 512; k += 4) {
    a0 = fmaf(hrow[k + 0], W1[(size_t)(k + 0) * 1024 + col], a0);
    a1 = fmaf(hrow[k + 1], W1[(size_t)(k + 1) * 1024 + col], a1);
    a2 = fmaf(hrow[k + 2], W1[(size_t)(k + 2) * 1024 + col], a2);
    a3 = fmaf(hrow[k + 3], W1[(size_t)(k + 3) * 1024 + col], a3);
  }
  const float v = a0 + a1 + a2 + a3 + b1[col];
  Y2[(size_t)p * 1024 + col] = v > 0.0f ? v : 0.0f;
}

__global__ __launch_bounds__(256) void kR2(const int* __restrict__ nrp,
                                           const float* __restrict__ Y2,
                                           const float* __restrict__ W2,
                                           const float* __restrict__ b2,
                                           float* __restrict__ F2) {
  const int p = blockIdx.y;
  if (p >= nrp[0]) return;
  const int col = blockIdx.x * 256 + threadIdx.x;
  __shared__ float yrow[1024];
  for (int c = threadIdx.x; c < 1024; c += 256) yrow[c] = Y2[(size_t)p * 1024 + c];
  __syncthreads();
  float a0 = 0, a1 = 0, a2 = 0, a3 = 0;
  #pragma unroll 4
  for (int k = 0; k < 1024; k += 4) {
    a0 = fmaf(yrow[k + 0], W2[(size_t)(k + 0) * 512 + col], a0);
    a1 = fmaf(yrow[k + 1], W2[(size_t)(k + 1) * 512 + col], a1);
    a2 = fmaf(yrow[k + 2], W2[(size_t)(k + 2) * 512 + col], a2);
    a3 = fmaf(yrow[k + 3], W2[(size_t)(k + 3) * 512 + col], a3);
  }
  F2[(size_t)p * 512 + col] = a0 + a1 + a2 + a3 + b2[col];
}

__global__ void kR3(const int* __restrict__ nrp, const float* __restrict__ H2,
                    const float* __restrict__ F2, const float* __restrict__ ln_g,
                    const float* __restrict__ ln_b, const float* __restrict__ wgm,
                    const float* __restrict__ consts, float* __restrict__ LNR,
                    float* __restrict__ cscore) {
  const int p = blockIdx.x;
  if (p >= nrp[0]) return;
  const int tid = threadIdx.x;  // 256
  const int c0 = tid, c1 = tid + 256;
  const float z0 = H2[(size_t)p * 512 + c0] + F2[(size_t)p * 512 + c0];
  const float z1 = H2[(size_t)p * 512 + c1] + F2[(size_t)p * 512 + c1];
  float s1 = z0 + z1, s2 = z0 * z0 + z1 * z1;
  #pragma unroll
  for (int s = 1; s < 64; s <<= 1) { s1 += __shfl_xor(s1, s); s2 += __shfl_xor(s2, s); }
  __shared__ float red[4][2];
  __shared__ float stats[2];
  const int wv = tid >> 6, ln = tid & 63;
  if (ln == 0) { red[wv][0] = s1; red[wv][1] = s2; }
  __syncthreads();
  if (tid == 0) {
    const float S1 = red[0][0] + red[1][0] + red[2][0] + red[3][0];
    const float S2 = red[0][1] + red[1][1] + red[2][1] + red[3][1];
    const float mu = S1 * (1.0f / 512.0f);
    const float var = S2 * (1.0f / 512.0f) - mu * mu;
    stats[0] = mu; stats[1] = rsqrtf(var + 1e-5f);
  }
  __syncthreads();
  const float mu = stats[0], rstd = stats[1];
  const float l0 = (z0 - mu) * rstd * ln_g[c0] + ln_b[c0];
  const float l1 = (z1 - mu) * rstd * ln_g[c1] + ln_b[c1];
  LNR[(size_t)p * 512 + c0] = l0;
  LNR[(size_t)p * 512 + c1] = l1;
  float sp = l0 * wgm[c0] + l1 * wgm[c1];
  #pragma unroll
  for (int s = 1; s < 64; s <<= 1) sp += __shfl_xor(sp, s);
  if (ln == 0) red[wv][0] = sp;
  __syncthreads();
  if (tid == 0) cscore[p] = red[0][0] + red[1][0] + red[2][0] + red[3][0] + consts[2];
}

// ---------------- exact select + attention -> ctx (+ bf16 copy) ----------------
__global__ void kSel(const int* __restrict__ ccnt, const int* __restrict__ offs,
                     const int* __restrict__ rowsl, const int* __restrict__ plast,
                     const float* __restrict__ cscore, const float* __restrict__ LNR,
                     const float* __restrict__ Wr, const float* __restrict__ br,
                     float* __restrict__ ctx, ushortT* __restrict__ ctxB) {
  const int b = blockIdx.x, tid = threadIdx.x;  // 256
  __shared__ int psel[4];
  __shared__ float lnl[512];
  __shared__ float qs[512];
  __shared__ float aw[4];
  __shared__ float red[4][4];
  if (tid == 0) {
    const int cnt = ccnt[b], off = offs[b];
    float scv[24]; int lr[24]; bool tk[24];
    for (int j = 0; j < cnt; ++j) { scv[j] = cscore[off + j]; lr[j] = rowsl[off + j]; tk[j] = false; }
    for (int k = 0; k < 4; ++k) {
      int best = -1;
      for (int j = 0; j < cnt; ++j) {
        if (tk[j]) continue;
        if (best < 0 || scv[j] > scv[best] || (scv[j] == scv[best] && lr[j] < lr[best])) best = j;
      }
      tk[best] = true;
      psel[k] = off + best;
    }
  }
  __syncthreads();
  const int pl = plast[b];
  for (int c = tid; c < 512; c += 256) lnl[c] = LNR[(size_t)pl * 512 + c];
  __syncthreads();
  #pragma unroll
  for (int cc = 0; cc < 2; ++cc) {
    const int col = tid + cc * 256;
    float s = br[col];
    for (int d = 0; d < 512; ++d) s = fmaf(lnl[d], Wr[(size_t)d * 512 + col], s);
    qs[col] = s;
  }
  __syncthreads();
  const int p0 = psel[0], p1 = psel[1], p2 = psel[2], p3 = psel[3];
  float ps[4] = {0, 0, 0, 0};
  for (int d = tid; d < 512; d += 256) {
    const float qv = qs[d];
    ps[0] = fmaf(qv, LNR[(size_t)p0 * 512 + d], ps[0]);
    ps[1] = fmaf(qv, LNR[(size_t)p1 * 512 + d], ps[1]);
    ps[2] = fmaf(qv, LNR[(size_t)p2 * 512 + d], ps[2]);
    ps[3] = fmaf(qv, LNR[(size_t)p3 * 512 + d], ps[3]);
  }
  #pragma unroll
  for (int s = 1; s < 64; s <<= 1) {
    ps[0] += __shfl_xor(ps[0], s); ps[1] += __shfl_xor(ps[1], s);
    ps[2] += __shfl_xor(ps[2], s); ps[3] += __shfl_xor(ps[3], s);
  }
  const int wv = tid >> 6, ln = tid & 63;
  if (ln == 0) { red[wv][0] = ps[0]; red[wv][1] = ps[1]; red[wv][2] = ps[2]; red[wv][3] = ps[3]; }
  __syncthreads();
  if (tid == 0) {
    const float s0 = red[0][0] + red[1][0] + red[2][0] + red[3][0];
    const float s1 = red[0][1] + red[1][1] + red[2][1] + red[3][1];
    const float s2 = red[0][2] + red[1][2] + red[2][2] + red[3][2];
    const float s3 = red[0][3] + red[1][3] + red[2][3] + red[3][3];
    const float m = fmaxf(fmaxf(fmaxf(s0, s1), fmaxf(s2, s3)), 0.0f);
    const float e0 = expf(s0 - m), e1 = expf(s1 - m), e2 = expf(s2 - m), e3 = expf(s3 - m);
    const float den = e0 + e1 + e2 + e3 + 12.0f * expf(-m);
    aw[0] = e0 / den; aw[1] = e1 / den; aw[2] = e2 / den; aw[3] = e3 / den;
  }
  __syncthreads();
  const float a0 = aw[0], a1 = aw[1], a2 = aw[2], a3 = aw[3];
  #pragma unroll
  for (int cc = 0; cc < 2; ++cc) {
    const int col = tid + cc * 256;
    const float v = a0 * LNR[(size_t)p0 * 512 + col] + a1 * LNR[(size_t)p1 * 512 + col]
                  + a2 * LNR[(size_t)p2 * 512 + col] + a3 * LNR[(size_t)p3 * 512 + col];
    ctx[(size_t)b * 512 + col] = v;
    ctxB[(size_t)b * 512 + col] = f2bf(v);
  }
}

// ---------------- out = ctx @ Wo + bo via MFMA 32x32x16, split-K=4 ----------------
__global__ __launch_bounds__(512) void kOutM(const ushortT* __restrict__ ctxB,
                                             const float* __restrict__ Wo,
                                             float* __restrict__ partial) {
  const int tid = threadIdx.x, w = tid >> 6, l = tid & 63;
  const int ky = blockIdx.y;                 // K-quarter
  int col = blockIdx.x * 256 + w * 32 + (l & 31);
  const bool cv = col < 50257;
  if (!cv) col = 50256;
  const int kg = (l >> 5) * 8;
  const int kb = ky * 128;
  bf16x8 afr[8];
  #pragma unroll
  for (int ks = 0; ks < 8; ++ks)
    afr[ks] = *(const bf16x8*)&ctxB[(size_t)(l & 31) * 512 + kb + ks * 16 + kg];
  f32x16 acc = {};
  #pragma unroll
  for (int ks = 0; ks < 8; ++ks) {
    const float* wp = Wo + (size_t)(kb + ks * 16 + kg) * 50257 + col;
    float wv[8];
    #pragma unroll
    for (int j = 0; j < 8; ++j) wv[j] = wp[(size_t)j * 50257];
    bf16x8 bfr;
    #pragma unroll
    for (int j = 0; j < 8; ++j) bfr[j] = (short)f2bf(wv[j]);
    acc = __builtin_amdgcn_mfma_f32_32x32x16_bf16(afr[ks], bfr, acc, 0, 0, 0);
  }
  if (cv) {
    #pragma unroll
    for (int r = 0; r < 16; ++r) {
      const int row = (r & 3) + 8 * (r >> 2) + 4 * (l >> 5);
      partial[((size_t)ky * 32 + row) * 50257 + col] = acc[r];
    }
  }
}

__global__ __launch_bounds__(256) void kOutRed(const float* __restrict__ partial,
                                               const float* __restrict__ bo,
                                               float* __restrict__ out) {
  const size_t i = (size_t)blockIdx.x * 256 + threadIdx.x;
  if (i >= (size_t)32 * 50257) return;
  const int col = (int)(i % 50257);
  float s = bo[col];
  #pragma unroll
  for (int q = 0; q < 4; ++q) s += partial[(size_t)q * 32 * 50257 + i];
  out[i] = s;
}

// ---------------- launch ----------------
extern "C" void kernel_launch(void* const* d_in, const int* in_sizes, int n_in,
                              void* d_out, int out_size, void* d_ws, size_t ws_size,
                              hipStream_t stream) {
  const int*   seq   = (const int*)  d_in[0];
  const float* embed = (const float*)d_in[1];
  const float* W1    = (const float*)d_in[2];
  const float* b1    = (const float*)d_in[3];
  const float* W2    = (const float*)d_in[4];
  const float* b2    = (const float*)d_in[5];
  const float* ln_g  = (const float*)d_in[6];
  const float* ln_b  = (const float*)d_in[7];
  const float* Wg    = (const float*)d_in[8];
  const float* bg    = (const float*)d_in[9];
  const float* Wr    = (const float*)d_in[10];
  const float* br    = (const float*)d_in[11];
  const float* Wo    = (const float*)d_in[12];
  const float* bo    = (const float*)d_in[13];
  float* out = (float*)d_out;
  char* ws = (char*)d_ws;

  ushortT* W1t   = (ushortT*)(ws + 0);
  ushortT* W2t   = (ushortT*)(ws + 1048576);
  float* gw      = (float*)(ws + 2097152);
  float* wgm     = (float*)(ws + 2099200);
  float* consts  = (float*)(ws + 2101248);
  ushortT* h     = (ushortT*)(ws + 2101504);     // 65536 x 512 bf16
  ushortT* Ybuf  = (ushortT*)(ws + 69210368);    // 32768 x 1024 bf16 (per chunk); dead after kG2p
  float* partial = (float*)(ws + 69210368);      // 4 x 32 x 50257 f32 (reuses Ybuf region, post-GEMM)
  float* scores  = (float*)(ws + 136319232);     // 65536 f32
  int* cidx      = (int*)(ws + 136581376);       // 32 x 24
  int* ccnt      = (int*)(ws + 136584448);
  int* offs      = (int*)(ws + 136584576);
  int* nrp       = (int*)(ws + 136584832);
  int* plast     = (int*)(ws + 136585088);
  int* rowsb     = (int*)(ws + 136585344);       // 832
  int* rowsl     = (int*)(ws + 136588672);       // 832
  float* partS   = (float*)(ws + 136592000);     // 65536 x 8 f32 (2MB); dead after kTop,
  float* H2      = (float*)(ws + 136592000);     //   then rescue buffers reuse the region
  float* Y2      = (float*)(ws + 138295936);     // 832 x 1024
  float* F2      = (float*)(ws + 141703808);     // 832 x 512
  float* LNR     = (float*)(ws + 143407744);     // 832 x 512
  float* csc     = (float*)(ws + 145111680);     // 832
  float* ctxb    = (float*)(ws + 145115008);     // 32 x 512 f32
  ushortT* ctxB  = (ushortT*)(ws + 145180544);   // 32 x 512 bf16

  kPrep <<<257, 256, 0, stream>>>(W1, W2, Wg, ln_g, W1t, W2t, gw, wgm);
  kPrep2<<<1, 512, 0, stream>>>(gw, wgm, ln_b, bg, consts);
  kEmbed<<<16384, 256, 0, stream>>>(seq, embed, h);
  for (int c = 0; c < 2; ++c) {
    kG1p<<<512, 512, 0, stream>>>(h + (size_t)c * 32768 * 512, W1t, b1, Ybuf);
    kG2p<<<256, 512, 0, stream>>>(Ybuf, W2t, h, b2, gw, partS, c * 32768);
  }
  kTop    <<<32, 256, 0, stream>>>(partS, consts, scores, cidx, ccnt);
  kCompact<<<1, 64, 0, stream>>>(ccnt, cidx, offs, rowsb, rowsl, plast, nrp);
  kR1<<<dim3(4, 800), 256, 0, stream>>>(nrp, rowsb, rowsl, seq, embed, H2, W1, b1, Y2);
  kR2<<<dim3(2, 800), 256, 0, stream>>>(nrp, Y2, W2, b2, F2);
  kR3<<<800, 256, 0, stream>>>(nrp, H2, F2, ln_g, ln_b, wgm, consts, LNR, csc);
  kSel<<<32, 256, 0, stream>>>(ccnt, offs, rowsl, plast, csc, LNR, Wr, br, ctxb, ctxB);
  kOutM<<<dim3(197, 4), 512, 0, stream>>>(ctxB, Wo, partial);
  kOutRed<<<(32 * 50257 + 255) / 256, 256, 0, stream>>>(partial, bo, out);
}

// Round 19
// 429.309 us; speedup vs baseline: 1.0224x; 1.0113x over previous
//
#include <hip/hip_runtime.h>
#include <stdint.h>

typedef __attribute__((ext_vector_type(8))) short bf16x8;
typedef __attribute__((ext_vector_type(4))) float f32x4;
typedef __attribute__((ext_vector_type(16))) float f32x16;
typedef unsigned short ushortT;

#define DEV static __device__ __forceinline__

DEV unsigned short f2bf(float x) {
  union { float f; unsigned u; } v; v.f = x;
  unsigned r = v.u + 0x7fffu + ((v.u >> 16) & 1u);
  return (unsigned short)(r >> 16);
}
DEV float bf2f(unsigned short b) {
  union { unsigned u; float f; } v; v.u = ((unsigned)b) << 16; return v.f;
}
DEV void gll16(const void* g, void* l) {
  __builtin_amdgcn_global_load_lds((const __attribute__((address_space(1))) void*)g,
                                   (__attribute__((address_space(3))) void*)l, 16, 0, 0);
}

#define VMW(n) asm volatile("s_waitcnt vmcnt(" #n ")" ::: "memory")
#define RAWBAR() __builtin_amdgcn_s_barrier()
#define SCHED0() __builtin_amdgcn_sched_barrier(0)

// ---------------- prep: coalesced LDS-tile transposes + gate fold ----------------
__global__ __launch_bounds__(256) void kPrep(const float* __restrict__ W1,
                                             const float* __restrict__ W2,
                                             const float* __restrict__ Wg,
                                             const float* __restrict__ ln_g,
                                             ushortT* __restrict__ W1t,
                                             ushortT* __restrict__ W2t,
                                             float* __restrict__ gw,
                                             float* __restrict__ wgm) {
  __shared__ ushortT T[64][65];
  const int tid = threadIdx.x, bb = blockIdx.x;
  if (bb < 128) {              // W1 [512 k][1024 n] -> W1t [1024 n][512 k]
    const int nt = bb & 15, kt = bb >> 4;      // 16 n-tiles x 8 k-tiles
    const int k0 = kt * 64, n0 = nt * 64;
    #pragma unroll
    for (int it = 0; it < 16; ++it) {
      const int r = it * 4 + (tid >> 6);
      const int c = tid & 63;
      T[c][r] = f2bf(W1[(size_t)(k0 + r) * 1024 + n0 + c]);
    }
    __syncthreads();
    #pragma unroll
    for (int it = 0; it < 16; ++it) {
      const int r = it * 4 + (tid >> 6);
      const int c = tid & 63;
      W1t[(size_t)(n0 + r) * 512 + k0 + c] = T[r][c];
    }
  } else if (bb < 256) {       // W2 [1024 k][512 n] -> W2t [512 n][1024 k]
    const int u = bb - 128;
    const int nt = u & 7, kt = u >> 3;         // 8 n-tiles x 16 k-tiles
    const int k0 = kt * 64, n0 = nt * 64;
    #pragma unroll
    for (int it = 0; it < 16; ++it) {
      const int r = it * 4 + (tid >> 6);
      const int c = tid & 63;
      T[c][r] = f2bf(W2[(size_t)(k0 + r) * 512 + n0 + c]);
    }
    __syncthreads();
    #pragma unroll
    for (int it = 0; it < 16; ++it) {
      const int r = it * 4 + (tid >> 6);
      const int c = tid & 63;
      W2t[(size_t)(n0 + r) * 1024 + k0 + c] = T[r][c];
    }
  } else {                     // gate fold
    for (int c = tid; c < 512; c += 256) {
      float s = 0.f;
      for (int j = 0; j < 16; ++j) s += Wg[c * 16 + j];
      const float m = s * (1.0f / 16.0f);
      wgm[c] = m;
      gw[c] = ln_g[c] * m;
    }
  }
}

// ---------------- embed gather -> h bf16 ----------------
__global__ void kEmbed(const int* __restrict__ seq, const float* __restrict__ embed,
                       ushortT* __restrict__ h) {
  const size_t t = (size_t)blockIdx.x * 256 + threadIdx.x;  // 4,194,304
  const size_t row = t >> 6;
  const int seg = (int)(t & 63) * 8;
  const int tok = seq[row];
  const float4* src = (const float4*)(embed + (size_t)tok * 512 + seg);
  float4 x = src[0], y = src[1];
  uint4 u;
  u.x = (unsigned)f2bf(x.x) | ((unsigned)f2bf(x.y) << 16);
  u.y = (unsigned)f2bf(x.z) | ((unsigned)f2bf(x.w) << 16);
  u.z = (unsigned)f2bf(y.x) | ((unsigned)f2bf(y.y) << 16);
  u.w = (unsigned)f2bf(y.z) | ((unsigned)f2bf(y.w) << 16);
  *(uint4*)(h + row * 512 + seg) = u;
}

// ============ GEMM1: 256x256 block, BK=32, 8 waves (64x128 wave tile), ring-2 ============
__global__ __launch_bounds__(512, 2) void kG1p(const ushortT* __restrict__ h,
                                               const ushortT* __restrict__ W1t,
                                               const float* __restrict__ b1,
                                               ushortT* __restrict__ Y) {
  __shared__ __align__(16) ushortT SH[32768];       // 64 KB: ring-2 A|B, then C-bounce
  const int tid = threadIdx.x, w = tid >> 6, l = tid & 63;
  const int b = blockIdx.x, xcd = b & 7, loc = b >> 3;   // loc 0..63
  const int nt = loc & 3, mtl = loc >> 2;
  const size_t m0 = (size_t)(xcd * 16 + mtl) * 256;
  const int n0 = nt * 256;
  const int rl = l & 15, gq = l >> 4;
  f32x4 acc[4][8] = {};

  auto stage = [&](int buf, int k0) {
    #pragma unroll
    for (int q = 0; q < 2; ++q) {
      const int c = w * 2 + q;                       // rowblock 0..15
      gll16(h + (m0 + c * 16 + rl) * 512 + k0 + gq * 8, &SH[buf * 8192 + c * 512]);
      gll16(W1t + (size_t)(n0 + c * 16 + rl) * 512 + k0 + gq * 8, &SH[16384 + buf * 8192 + c * 512]);
    }
  };

  const int wr = w >> 1, wc = w & 1, l8 = l * 8;
  auto compute = [&](int buf) {
    bf16x8 a[4], bb[8];
    #pragma unroll
    for (int i = 0; i < 4; ++i)
      a[i] = *(const bf16x8*)&SH[buf * 8192 + (wr * 4 + i) * 512 + l8];
    #pragma unroll
    for (int j = 0; j < 8; ++j)
      bb[j] = *(const bf16x8*)&SH[16384 + buf * 8192 + (wc * 8 + j) * 512 + l8];
    #pragma unroll
    for (int i = 0; i < 4; ++i)
      #pragma unroll
      for (int j = 0; j < 8; ++j)
        acc[i][j] = __builtin_amdgcn_mfma_f32_16x16x32_bf16(a[i], bb[j], acc[i][j], 0, 0, 0);
  };

  stage(0, 0); stage(1, 32);
  for (int t = 0; t < 14; ++t) {
    VMW(4); RAWBAR(); SCHED0();
    compute(t & 1);
    SCHED0(); RAWBAR();
    stage(t & 1, (t + 2) * 32);
  }
  VMW(4); RAWBAR(); SCHED0(); compute(0); SCHED0(); RAWBAR();   // t=14
  VMW(0); RAWBAR(); SCHED0(); compute(1);                       // t=15

  float bv[8];
  #pragma unroll
  for (int j = 0; j < 8; ++j) bv[j] = b1[n0 + wc * 128 + j * 16 + rl];

  // LDS-bounce epilogue: 4 passes of 64 rows, row stride 266 ushorts
  #pragma unroll
  for (int P = 0; P < 4; ++P) {
    __syncthreads();
    if (wr == P) {
      #pragma unroll
      for (int i = 0; i < 4; ++i) {
        #pragma unroll
        for (int j = 0; j < 8; ++j) {
          const int cl = wc * 128 + j * 16 + rl;
          #pragma unroll
          for (int r = 0; r < 4; ++r) {
            const int lr = i * 16 + gq * 4 + r;
            float v = acc[i][j][r] + bv[j];
            v = v > 0.0f ? v : 0.0f;
            SH[lr * 266 + cl] = f2bf(v);
          }
        }
      }
    }
    __syncthreads();
    #pragma unroll
    for (int it = 0; it < 4; ++it) {
      const int row = it * 16 + (tid >> 5);
      const int c8 = (tid & 31) * 8;
      uint4 v = *(const uint4*)&SH[row * 266 + c8];
      *(uint4*)&Y[(m0 + P * 64 + row) * 1024 + n0 + c8] = v;
    }
  }
}

// ---------------- GEMM2: z = Y@W2+b2+h -> partial LN stats; ring-2 ----------------
__global__ __launch_bounds__(512, 2) void kG2p(const ushortT* __restrict__ Yb,
                                               const ushortT* __restrict__ W2t,
                                               const ushortT* __restrict__ h,
                                               const float* __restrict__ b2,
                                               const float* __restrict__ gw,
                                               float* __restrict__ partS, int R0) {
  __shared__ __align__(16) ushortT As[2][256 * 32];
  __shared__ __align__(16) ushortT Bs[2][256 * 32];
  __shared__ float part[256][2][3];
  const int tid = threadIdx.x, w = tid >> 6, l = tid & 63;
  const int b = blockIdx.x, xcd = b & 7, loc = b >> 3;   // loc 0..31
  const int nt = loc & 1, mtl = loc >> 1;
  const size_t m0 = (size_t)(xcd * 16 + mtl) * 256;
  const int n0 = nt * 256;
  const int rl = l & 15, gq = l >> 4;
  f32x4 acc[4][8] = {};

  auto stage = [&](int buf, int k0) {
    #pragma unroll
    for (int q = 0; q < 2; ++q) {
      const int c = w * 2 + q;
      gll16(Yb + (m0 + c * 16 + rl) * 1024 + k0 + gq * 8, &As[buf][c * 512]);
      gll16(W2t + (size_t)(n0 + c * 16 + rl) * 1024 + k0 + gq * 8, &Bs[buf][c * 512]);
    }
  };

  const int wr = w >> 1, wc = w & 1, l8 = l * 8;
  auto compute = [&](int buf) {
    bf16x8 a[4], bb[8];
    #pragma unroll
    for (int i = 0; i < 4; ++i)
      a[i] = *(const bf16x8*)&As[buf][(wr * 4 + i) * 512 + l8];
    #pragma unroll
    for (int j = 0; j < 8; ++j)
      bb[j] = *(const bf16x8*)&Bs[buf][(wc * 8 + j) * 512 + l8];
    #pragma unroll
    for (int i = 0; i < 4; ++i)
      #pragma unroll
      for (int j = 0; j < 8; ++j)
        acc[i][j] = __builtin_amdgcn_mfma_f32_16x16x32_bf16(a[i], bb[j], acc[i][j], 0, 0, 0);
  };

  stage(0, 0); stage(1, 32);
  for (int t = 0; t < 30; ++t) {
    VMW(4); RAWBAR(); SCHED0();
    compute(t & 1);
    SCHED0(); RAWBAR();
    stage(t & 1, (t + 2) * 32);
  }
  VMW(4); RAWBAR(); SCHED0(); compute(0); SCHED0(); RAWBAR();   // t=30
  VMW(0); RAWBAR(); SCHED0(); compute(1);                       // t=31

  // epilogue: exact partial stats over this block's 256 cols
  #pragma unroll
  for (int i = 0; i < 4; ++i) {
    #pragma unroll
    for (int r = 0; r < 4; ++r) {
      const int rowl = wr * 64 + i * 16 + gq * 4 + r;
      const size_t grow = (size_t)R0 + m0 + rowl;
      float s1 = 0, s2 = 0, s3 = 0;
      #pragma unroll
      for (int j = 0; j < 8; ++j) {
        const int col = n0 + wc * 128 + j * 16 + rl;
        const float z = acc[i][j][r] + b2[col] + bf2f(h[grow * 512 + col]);
        s1 += z; s2 += z * z; s3 += z * gw[col];
      }
      #pragma unroll
      for (int s = 1; s < 16; s <<= 1) {
        s1 += __shfl_xor(s1, s);
        s2 += __shfl_xor(s2, s);
        s3 += __shfl_xor(s3, s);
      }
      if (rl == 0) { part[rowl][wc][0] = s1; part[rowl][wc][1] = s2; part[rowl][wc][2] = s3; }
    }
  }
  __syncthreads();
  if (tid < 256) {
    const size_t grow = (size_t)R0 + m0 + tid;
    const float S1 = part[tid][0][0] + part[tid][1][0];
    const float S2 = part[tid][0][1] + part[tid][1][1];
    const float S3 = part[tid][0][2] + part[tid][1][2];
    float* p = partS + grow * 8 + nt * 4;
    p[0] = S1; p[1] = S2; p[2] = S3;
  }
}

// ---------------- fold partials -> score (registers); top-4 + margin candidates ----------------
// Computes Cg/Cb per block (was kPrep2); scores kept in sv[8] registers.
__global__ void kTop(const float* __restrict__ partS, const float* __restrict__ gw,
                     const float* __restrict__ wgm, const float* __restrict__ ln_b,
                     const float* __restrict__ bg,
                     int* __restrict__ cidx, int* __restrict__ ccnt) {
  const int b = blockIdx.x, tid = threadIdx.x;   // 256
  // per-block consts: Cg = sum(gw), Cb = sum(ln_b*wgm) + mean(bg)
  float ca = gw[tid] + gw[tid + 256];
  float cc = ln_b[tid] * wgm[tid] + ln_b[tid + 256] * wgm[tid + 256];
  #pragma unroll
  for (int s = 1; s < 64; s <<= 1) { ca += __shfl_xor(ca, s); cc += __shfl_xor(cc, s); }
  __shared__ float cred[4][2];
  __shared__ float cs[2];
  {
    const int wv = tid >> 6, ln = tid & 63;
    if (ln == 0) { cred[wv][0] = ca; cred[wv][1] = cc; }
  }
  __syncthreads();
  if (tid == 0) {
    float Cg = cred[0][0] + cred[1][0] + cred[2][0] + cred[3][0];
    float Cb0 = cred[0][1] + cred[1][1] + cred[2][1] + cred[3][1];
    float bgm = 0;
    #pragma unroll
    for (int j = 0; j < 16; ++j) bgm += bg[j];
    cs[0] = Cg; cs[1] = Cb0 + bgm * (1.0f / 16.0f);
  }
  __syncthreads();
  const float Cg = cs[0], Cb = cs[1];

  float sv[8];
  float v0 = -1e30f, v1 = -1e30f, v2 = -1e30f, v3 = -1e30f;
  #pragma unroll
  for (int q = 0; q < 8; ++q) {
    const int i = tid + q * 256;
    float x = -1e30f;
    if (i < 2047) {
      const float* p = partS + ((size_t)b * 2048 + i) * 8;
      const float S1 = p[0] + p[4];
      const float S2 = p[1] + p[5];
      const float S3 = p[2] + p[6];
      const float mu = S1 * (1.0f / 512.0f);
      const float var = S2 * (1.0f / 512.0f) - mu * mu;
      x = rsqrtf(var + 1e-5f) * (S3 - mu * Cg) + Cb;
    }
    sv[q] = x;
    if (x > v3) {
      if (x > v0)      { v3 = v2; v2 = v1; v1 = v0; v0 = x; }
      else if (x > v1) { v3 = v2; v2 = v1; v1 = x; }
      else if (x > v2) { v3 = v2; v2 = x; }
      else             { v3 = x; }
    }
  }
  __shared__ float lv[256][4];
  lv[tid][0] = v0; lv[tid][1] = v1; lv[tid][2] = v2; lv[tid][3] = v3;
  __syncthreads();
  for (int s = 128; s > 0; s >>= 1) {
    if (tid < s) {
      float m[8] = { lv[tid][0], lv[tid][1], lv[tid][2], lv[tid][3],
                     lv[tid + s][0], lv[tid + s][1], lv[tid + s][2], lv[tid + s][3] };
      #pragma unroll
      for (int k = 0; k < 4; ++k) {
        int mx = k;
        #pragma unroll
        for (int j2 = k + 1; j2 < 8; ++j2) if (m[j2] > m[mx]) mx = j2;
        const float tv = m[k]; m[k] = m[mx]; m[mx] = tv;
        lv[tid][k] = m[k];
      }
    }
    __syncthreads();
  }
  __shared__ int cnt;
  __shared__ float thr;
  if (tid == 0) { thr = lv[0][3] - 0.03f; cnt = 0; }
  __syncthreads();
  const float th = thr;
  #pragma unroll
  for (int q = 0; q < 8; ++q) {
    const int i = tid + q * 256;
    if (i < 2047 && sv[q] >= th) {
      const int p = atomicAdd(&cnt, 1);
      if (p < 24) cidx[b * 24 + p] = i;
    }
  }
  __syncthreads();
  if (tid == 0) ccnt[b] = cnt < 24 ? cnt : 24;
}

__global__ void kCompact(const int* __restrict__ ccnt, const int* __restrict__ cidx,
                         int* __restrict__ offs, int* __restrict__ rowsb,
                         int* __restrict__ rowsl, int* __restrict__ plast,
                         int* __restrict__ nrp) {
  const int tid = threadIdx.x;
  if (tid >= 32) return;
  int off = 0, nc = 0;
  for (int k = 0; k < 32; ++k) { const int c = ccnt[k]; if (k < tid) off += c; nc += c; }
  offs[tid] = off;
  const int cnt = ccnt[tid];
  for (int j = 0; j < cnt; ++j) { rowsb[off + j] = tid; rowsl[off + j] = cidx[tid * 24 + j]; }
  rowsb[nc + tid] = tid; rowsl[nc + tid] = 2047; plast[tid] = nc + tid;
  if (tid == 0) { offs[32] = nc; nrp[0] = nc + 32; }
}

// ---------------- exact f32 rescue path (gather fused into kR1) ----------------
__global__ __launch_bounds__(256) void kR1(const int* __restrict__ nrp,
                                           const int* __restrict__ rowsb,
                                           const int* __restrict__ rowsl,
                                           const int* __restrict__ seq,
                                           const float* __restrict__ embed,
                                           float* __restrict__ H2,
                                           const float* __restrict__ W1,
                                           const float* __restrict__ b1,
                                           float* __restrict__ Y2) {
  const int p = blockIdx.y;
  if (p >= nrp[0]) return;
  const int b = rowsb[p], lr = rowsl[p];
  const int tok = seq[(size_t)b * 2048 + lr];
  const float* src = embed + (size_t)tok * 512;
  const int col = blockIdx.x * 256 + threadIdx.x;
  __shared__ float hrow[512];
  for (int c = threadIdx.x; c < 512; c += 256) {
    const float v = src[c];
    hrow[c] = v;
    if (blockIdx.x == 0) H2[(size_t)p * 512 + c] = v;
  }
  __syncthreads();
  float a0 = 0, a1 = 0, a2 = 0, a3 = 0;
  #pragma unroll 4
  for (int k = 0; k < 512; k += 4) {
    a0 = fmaf(hrow[k + 0], W1[(size_t)(k + 0) * 1024 + col], a0);
    a1 = fmaf(hrow[k + 1], W1[(size_t)(k + 1) * 1024 + col], a1);
    a2 = fmaf(hrow[k + 2], W1[(size_t)(k + 2) * 1024 + col], a2);
    a3 = fmaf(hrow[k + 3], W1[(size_t)(k + 3) * 1024 + col], a3);
  }
  const float v = a0 + a1 + a2 + a3 + b1[col];
  Y2[(size_t)p * 1024 + col] = v > 0.0f ? v : 0.0f;
}

__global__ __launch_bounds__(256) void kR2(const int* __restrict__ nrp,
                                           const float* __restrict__ Y2,
                                           const float* __restrict__ W2,
                                           const float* __restrict__ b2,
                                           float* __restrict__ F2) {
  const int p = blockIdx.y;
  if (p >= nrp[0]) return;
  const int col = blockIdx.x * 256 + threadIdx.x;
  __shared__ float yrow[1024];
  for (int c = threadIdx.x; c < 1024; c += 256) yrow[c] = Y2[(size_t)p * 1024 + c];
  __syncthreads();
  float a0 = 0, a1 = 0, a2 = 0, a3 = 0;
  #pragma unroll 4
  for (int k = 0; k < 1024; k += 4) {
    a0 = fmaf(yrow[k + 0], W2[(size_t)(k + 0) * 512 + col], a0);
    a1 = fmaf(yrow[k + 1], W2[(size_t)(k + 1) * 512 + col], a1);
    a2 = fmaf(yrow[k + 2], W2[(size_t)(k + 2) * 512 + col], a2);
    a3 = fmaf(yrow[k + 3], W2[(size_t)(k + 3) * 512 + col], a3);
  }
  F2[(size_t)p * 512 + col] = a0 + a1 + a2 + a3 + b2[col];
}

__global__ void kR3(const int* __restrict__ nrp, const float* __restrict__ H2,
                    const float* __restrict__ F2, const float* __restrict__ ln_g,
                    const float* __restrict__ ln_b, const float* __restrict__ wgm,
                    const float* __restrict__ bg, float* __restrict__ LNR,
                    float* __restrict__ cscore) {
  const int p = blockIdx.x;
  if (p >= nrp[0]) return;
  const int tid = threadIdx.x;  // 256
  const int c0 = tid, c1 = tid + 256;
  const float z0 = H2[(size_t)p * 512 + c0] + F2[(size_t)p * 512 + c0];
  const float z1 = H2[(size_t)p * 512 + c1] + F2[(size_t)p * 512 + c1];
  float s1 = z0 + z1, s2 = z0 * z0 + z1 * z1;
  #pragma unroll
  for (int s = 1; s < 64; s <<= 1) { s1 += __shfl_xor(s1, s); s2 += __shfl_xor(s2, s); }
  __shared__ float red[4][2];
  __shared__ float stats[2];
  const int wv = tid >> 6, ln = tid & 63;
  if (ln == 0) { red[wv][0] = s1; red[wv][1] = s2; }
  __syncthreads();
  if (tid == 0) {
    const float S1 = red[0][0] + red[1][0] + red[2][0] + red[3][0];
    const float S2 = red[0][1] + red[1][1] + red[2][1] + red[3][1];
    const float mu = S1 * (1.0f / 512.0f);
    const float var = S2 * (1.0f / 512.0f) - mu * mu;
    stats[0] = mu; stats[1] = rsqrtf(var + 1e-5f);
  }
  __syncthreads();
  const float mu = stats[0], rstd = stats[1];
  const float l0 = (z0 - mu) * rstd * ln_g[c0] + ln_b[c0];
  const float l1 = (z1 - mu) * rstd * ln_g[c1] + ln_b[c1];
  LNR[(size_t)p * 512 + c0] = l0;
  LNR[(size_t)p * 512 + c1] = l1;
  float sp = l0 * wgm[c0] + l1 * wgm[c1];
  #pragma unroll
  for (int s = 1; s < 64; s <<= 1) sp += __shfl_xor(sp, s);
  if (ln == 0) red[wv][0] = sp;
  __syncthreads();
  if (tid == 0) {
    float bgm = 0;
    #pragma unroll
    for (int j = 0; j < 16; ++j) bgm += bg[j];
    cscore[p] = red[0][0] + red[1][0] + red[2][0] + red[3][0] + bgm * (1.0f / 16.0f);
  }
}

// ---------------- exact select + attention -> ctx (+ bf16 copy) ----------------
__global__ void kSel(const int* __restrict__ ccnt, const int* __restrict__ offs,
                     const int* __restrict__ rowsl, const int* __restrict__ plast,
                     const float* __restrict__ cscore, const float* __restrict__ LNR,
                     const float* __restrict__ Wr, const float* __restrict__ br,
                     float* __restrict__ ctx, ushortT* __restrict__ ctxB) {
  const int b = blockIdx.x, tid = threadIdx.x;  // 256
  __shared__ int psel[4];
  __shared__ float lnl[512];
  __shared__ float qs[512];
  __shared__ float aw[4];
  __shared__ float red[4][4];
  if (tid == 0) {
    const int cnt = ccnt[b], off = offs[b];
    float scv[24]; int lr[24]; bool tk[24];
    for (int j = 0; j < cnt; ++j) { scv[j] = cscore[off + j]; lr[j] = rowsl[off + j]; tk[j] = false; }
    for (int k = 0; k < 4; ++k) {
      int best = -1;
      for (int j = 0; j < cnt; ++j) {
        if (tk[j]) continue;
        if (best < 0 || scv[j] > scv[best] || (scv[j] == scv[best] && lr[j] < lr[best])) best = j;
      }
      tk[best] = true;
      psel[k] = off + best;
    }
  }
  __syncthreads();
  const int pl = plast[b];
  for (int c = tid; c < 512; c += 256) lnl[c] = LNR[(size_t)pl * 512 + c];
  __syncthreads();
  #pragma unroll
  for (int cc = 0; cc < 2; ++cc) {
    const int col = tid + cc * 256;
    float s = br[col];
    for (int d = 0; d < 512; ++d) s = fmaf(lnl[d], Wr[(size_t)d * 512 + col], s);
    qs[col] = s;
  }
  __syncthreads();
  const int p0 = psel[0], p1 = psel[1], p2 = psel[2], p3 = psel[3];
  float ps[4] = {0, 0, 0, 0};
  for (int d = tid; d < 512; d += 256) {
    const float qv = qs[d];
    ps[0] = fmaf(qv, LNR[(size_t)p0 * 512 + d], ps[0]);
    ps[1] = fmaf(qv, LNR[(size_t)p1 * 512 + d], ps[1]);
    ps[2] = fmaf(qv, LNR[(size_t)p2 * 512 + d], ps[2]);
    ps[3] = fmaf(qv, LNR[(size_t)p3 * 512 + d], ps[3]);
  }
  #pragma unroll
  for (int s = 1; s < 64; s <<= 1) {
    ps[0] += __shfl_xor(ps[0], s); ps[1] += __shfl_xor(ps[1], s);
    ps[2] += __shfl_xor(ps[2], s); ps[3] += __shfl_xor(ps[3], s);
  }
  const int wv = tid >> 6, ln = tid & 63;
  if (ln == 0) { red[wv][0] = ps[0]; red[wv][1] = ps[1]; red[wv][2] = ps[2]; red[wv][3] = ps[3]; }
  __syncthreads();
  if (tid == 0) {
    const float s0 = red[0][0] + red[1][0] + red[2][0] + red[3][0];
    const float s1 = red[0][1] + red[1][1] + red[2][1] + red[3][1];
    const float s2 = red[0][2] + red[1][2] + red[2][2] + red[3][2];
    const float s3 = red[0][3] + red[1][3] + red[2][3] + red[3][3];
    const float m = fmaxf(fmaxf(fmaxf(s0, s1), fmaxf(s2, s3)), 0.0f);
    const float e0 = expf(s0 - m), e1 = expf(s1 - m), e2 = expf(s2 - m), e3 = expf(s3 - m);
    const float den = e0 + e1 + e2 + e3 + 12.0f * expf(-m);
    aw[0] = e0 / den; aw[1] = e1 / den; aw[2] = e2 / den; aw[3] = e3 / den;
  }
  __syncthreads();
  const float a0 = aw[0], a1 = aw[1], a2 = aw[2], a3 = aw[3];
  #pragma unroll
  for (int cc = 0; cc < 2; ++cc) {
    const int col = tid + cc * 256;
    const float v = a0 * LNR[(size_t)p0 * 512 + col] + a1 * LNR[(size_t)p1 * 512 + col]
                  + a2 * LNR[(size_t)p2 * 512 + col] + a3 * LNR[(size_t)p3 * 512 + col];
    ctx[(size_t)b * 512 + col] = v;
    ctxB[(size_t)b * 512 + col] = f2bf(v);
  }
}

// ---------------- out = ctx @ Wo + bo via MFMA 32x32x16, split-K=4 ----------------
__global__ __launch_bounds__(512) void kOutM(const ushortT* __restrict__ ctxB,
                                             const float* __restrict__ Wo,
                                             float* __restrict__ partial) {
  const int tid = threadIdx.x, w = tid >> 6, l = tid & 63;
  const int ky = blockIdx.y;                 // K-quarter
  int col = blockIdx.x * 256 + w * 32 + (l & 31);
  const bool cv = col < 50257;
  if (!cv) col = 50256;
  const int kg = (l >> 5) * 8;
  const int kb = ky * 128;
  bf16x8 afr[8];
  #pragma unroll
  for (int ks = 0; ks < 8; ++ks)
    afr[ks] = *(const bf16x8*)&ctxB[(size_t)(l & 31) * 512 + kb + ks * 16 + kg];
  f32x16 acc = {};
  #pragma unroll
  for (int ks = 0; ks < 8; ++ks) {
    const float* wp = Wo + (size_t)(kb + ks * 16 + kg) * 50257 + col;
    float wv[8];
    #pragma unroll
    for (int j = 0; j < 8; ++j) wv[j] = wp[(size_t)j * 50257];
    bf16x8 bfr;
    #pragma unroll
    for (int j = 0; j < 8; ++j) bfr[j] = (short)f2bf(wv[j]);
    acc = __builtin_amdgcn_mfma_f32_32x32x16_bf16(afr[ks], bfr, acc, 0, 0, 0);
  }
  if (cv) {
    #pragma unroll
    for (int r = 0; r < 16; ++r) {
      const int row = (r & 3) + 8 * (r >> 2) + 4 * (l >> 5);
      partial[((size_t)ky * 32 + row) * 50257 + col] = acc[r];
    }
  }
}

__global__ __launch_bounds__(256) void kOutRed(const float* __restrict__ partial,
                                               const float* __restrict__ bo,
                                               float* __restrict__ out) {
  const size_t i = (size_t)blockIdx.x * 256 + threadIdx.x;
  if (i >= (size_t)32 * 50257) return;
  const int col = (int)(i % 50257);
  float s = bo[col];
  #pragma unroll
  for (int q = 0; q < 4; ++q) s += partial[(size_t)q * 32 * 50257 + i];
  out[i] = s;
}

// ---------------- launch ----------------
extern "C" void kernel_launch(void* const* d_in, const int* in_sizes, int n_in,
                              void* d_out, int out_size, void* d_ws, size_t ws_size,
                              hipStream_t stream) {
  const int*   seq   = (const int*)  d_in[0];
  const float* embed = (const float*)d_in[1];
  const float* W1    = (const float*)d_in[2];
  const float* b1    = (const float*)d_in[3];
  const float* W2    = (const float*)d_in[4];
  const float* b2    = (const float*)d_in[5];
  const float* ln_g  = (const float*)d_in[6];
  const float* ln_b  = (const float*)d_in[7];
  const float* Wg    = (const float*)d_in[8];
  const float* bg    = (const float*)d_in[9];
  const float* Wr    = (const float*)d_in[10];
  const float* br    = (const float*)d_in[11];
  const float* Wo    = (const float*)d_in[12];
  const float* bo    = (const float*)d_in[13];
  float* out = (float*)d_out;
  char* ws = (char*)d_ws;

  ushortT* W1t   = (ushortT*)(ws + 0);
  ushortT* W2t   = (ushortT*)(ws + 1048576);
  float* gw      = (float*)(ws + 2097152);
  float* wgm     = (float*)(ws + 2099200);
  ushortT* h     = (ushortT*)(ws + 2101504);     // 65536 x 512 bf16
  ushortT* Ybuf  = (ushortT*)(ws + 69210368);    // 32768 x 1024 bf16 (per chunk); dead after kG2p
  float* partial = (float*)(ws + 69210368);      // 4 x 32 x 50257 f32 (reuses Ybuf region, post-GEMM)
  int* cidx      = (int*)(ws + 136581376);       // 32 x 24
  int* ccnt      = (int*)(ws + 136584448);
  int* offs      = (int*)(ws + 136584576);
  int* nrp       = (int*)(ws + 136584832);
  int* plast     = (int*)(ws + 136585088);
  int* rowsb     = (int*)(ws + 136585344);       // 832
  int* rowsl     = (int*)(ws + 136588672);       // 832
  float* partS   = (float*)(ws + 136592000);     // 65536 x 8 f32 (2MB); dead after kTop,
  float* H2      = (float*)(ws + 136592000);     //   then rescue buffers reuse the region
  float* Y2      = (float*)(ws + 138295936);     // 832 x 1024
  float* F2      = (float*)(ws + 141703808);     // 832 x 512
  float* LNR     = (float*)(ws + 143407744);     // 832 x 512
  float* csc     = (float*)(ws + 145111680);     // 832
  float* ctxb    = (float*)(ws + 145115008);     // 32 x 512 f32
  ushortT* ctxB  = (ushortT*)(ws + 145180544);   // 32 x 512 bf16

  kPrep <<<257, 256, 0, stream>>>(W1, W2, Wg, ln_g, W1t, W2t, gw, wgm);
  kEmbed<<<16384, 256, 0, stream>>>(seq, embed, h);
  for (int c = 0; c < 2; ++c) {
    kG1p<<<512, 512, 0, stream>>>(h + (size_t)c * 32768 * 512, W1t, b1, Ybuf);
    kG2p<<<256, 512, 0, stream>>>(Ybuf, W2t, h, b2, gw, partS, c * 32768);
  }
  kTop    <<<32, 256, 0, stream>>>(partS, gw, wgm, ln_b, bg, cidx, ccnt);
  kCompact<<<1, 64, 0, stream>>>(ccnt, cidx, offs, rowsb, rowsl, plast, nrp);
  kR1<<<dim3(4, 800), 256, 0, stream>>>(nrp, rowsb, rowsl, seq, embed, H2, W1, b1, Y2);
  kR2<<<dim3(2, 800), 256, 0, stream>>>(nrp, Y2, W2, b2, F2);
  kR3<<<800, 256, 0, stream>>>(nrp, H2, F2, ln_g, ln_b, wgm, bg, LNR, csc);
  kSel<<<32, 256, 0, stream>>>(ccnt, offs, rowsl, plast, csc, LNR, Wr, br, ctxb, ctxB);
  kOutM<<<dim3(197, 4), 512, 0, stream>>>(ctxB, Wo, partial);
  kOutRed<<<(32 * 50257 + 255) / 256, 256, 0, stream>>>(partial, bo, out);
}